// Round 11
// baseline (136.019 us; speedup 1.0000x reference)
//
#include <hip/hip_runtime.h>
#include <math.h>

#define NB_B 4
#define NB_N 8
#define NB_C 256
#define NB_K 16
#define NB_P 4096
#define NB_BN (NB_B * NB_N)

typedef float nfloat2 __attribute__((ext_vector_type(2)));  // NT-store-able

// workspace float offsets
#define WS_WSUM 0
#define WS_VSUM (NB_BN * NB_C)                    // 8192
#define WS_GT   (2 * NB_BN * NB_C)                // 16384
#define WS_DEN  (WS_GT + NB_B * NB_C)             // 17408
#define WS_NB   17440                             // normalized bank, [bn][c][k]
#define WS_PN   (WS_NB + NB_BN * NB_K * NB_C)     // 148512: proto_new, [bn][c][k]
#define WS_VAL  (WS_PN + NB_BN * NB_K * NB_C)     // 279584

// ---------------- block reduction helpers (blockDim == 256, 4 waves) ----------------
__device__ __forceinline__ float2 blk_sum2(float a, float b, float2* sbuf) {
#pragma unroll
  for (int off = 32; off > 0; off >>= 1) {
    a += __shfl_down(a, off, 64);
    b += __shfl_down(b, off, 64);
  }
  int lane = threadIdx.x & 63, wid = threadIdx.x >> 6;
  __syncthreads();
  if (lane == 0) sbuf[wid] = make_float2(a, b);
  __syncthreads();
  float2 r;
  r.x = sbuf[0].x + sbuf[1].x + sbuf[2].x + sbuf[3].x;
  r.y = sbuf[0].y + sbuf[1].y + sbuf[2].y + sbuf[3].y;
  return r;
}

__device__ __forceinline__ float2 blk_max2(float a, float b, float2* sbuf) {
#pragma unroll
  for (int off = 32; off > 0; off >>= 1) {
    a = fmaxf(a, __shfl_down(a, off, 64));
    b = fmaxf(b, __shfl_down(b, off, 64));
  }
  int lane = threadIdx.x & 63, wid = threadIdx.x >> 6;
  __syncthreads();
  if (lane == 0) sbuf[wid] = make_float2(a, b);
  __syncthreads();
  float2 r;
  r.x = fmaxf(fmaxf(sbuf[0].x, sbuf[1].x), fmaxf(sbuf[2].x, sbuf[3].x));
  r.y = fmaxf(fmaxf(sbuf[0].y, sbuf[1].y), fmaxf(sbuf[2].y, sbuf[3].y));
  return r;
}

// ---------------- robust decoding of the bool `valid` input ----------------
__device__ __forceinline__ int validMode(const void* vptr) {
  const unsigned int* w = (const unsigned int*)vptr;
  int mode = 0;  // 0 = int32
  for (int i = 0; i < 128; ++i) {
    unsigned int x = w[i];
    if (x == 0x3f800000u) return 2;      // float32 1.0 present -> f32
    if (x > 1u) mode = 1;                // packed bytes -> uint8
  }
  return mode;
}
__device__ __forceinline__ bool getValid(const void* vptr, int mode, int idx) {
  if (mode == 1) return ((const unsigned char*)vptr)[idx] != 0;
  if (mode == 2) return ((const float*)vptr)[idx] != 0.0f;
  return ((const int*)vptr)[idx] != 0;
}

// ---------------- kernel 1: big reductions over P (known-good) ----------------
__global__ __launch_bounds__(256) void k1_reduce(
    const float* __restrict__ value, const float* __restrict__ frame,
    const float* __restrict__ mask, float* __restrict__ ws) {
  __shared__ float2 sbuf[4];
  int gid = blockIdx.x, tid = threadIdx.x;
  if (gid < NB_BN * NB_C) {
    int bn = gid >> 8;
    const float4* v4 = (const float4*)(value + (size_t)gid * NB_P);
    const float4* m4 = (const float4*)(mask + (size_t)bn * NB_P);
    float wsum = 0.f, vsum = 0.f;
#pragma unroll
    for (int i = 0; i < NB_P / 4 / 256; ++i) {
      float4 a = v4[i * 256 + tid];
      float4 m = m4[i * 256 + tid];
      wsum += a.x * m.x + a.y * m.y + a.z * m.z + a.w * m.w;
      vsum += a.x + a.y + a.z + a.w;
    }
    float2 r = blk_sum2(wsum, vsum, sbuf);
    if (tid == 0) { ws[WS_WSUM + gid] = r.x; ws[WS_VSUM + gid] = r.y; }
  } else if (gid < NB_BN * NB_C + NB_B * NB_C) {
    int idx = gid - NB_BN * NB_C;
    const float4* f4 = (const float4*)(frame + (size_t)idx * NB_P);
    float s = 0.f;
#pragma unroll
    for (int i = 0; i < 4; ++i) {
      float4 a = f4[i * 256 + tid];
      s += a.x + a.y + a.z + a.w;
    }
    float2 r = blk_sum2(s, 0.f, sbuf);
    if (tid == 0) ws[WS_GT + idx] = r.x * (1.0f / NB_P);
  } else {
    int bn = gid - NB_BN * NB_C - NB_B * NB_C;
    const float4* m4 = (const float4*)(mask + (size_t)bn * NB_P);
    float s = 0.f;
#pragma unroll
    for (int i = 0; i < 4; ++i) {
      float4 a = m4[i * 256 + tid];
      s += a.x + a.y + a.z + a.w;
    }
    float2 r = blk_sum2(s, 0.f, sbuf);
    if (tid == 0) ws[WS_DEN + bn] = r.x;
  }
}

// ---------------- kernel 2: per-(b,n) policy + bank update ----------------
__global__ __launch_bounds__(256) void k2_policy(
    const float* __restrict__ proto, const float* __restrict__ age,
    const float* __restrict__ usage, const float* __restrict__ conf,
    const void* __restrict__ valid, const float* __restrict__ W1,
    const float* __restrict__ b1, const float* __restrict__ W2,
    const float* __restrict__ b2, float* __restrict__ ws,
    float* __restrict__ out_logits) {
  __shared__ float2 sbuf[4];
  __shared__ float s_cand[NB_C];
  __shared__ float s_sim[NB_K];
  __shared__ float s_invn[NB_K];
  __shared__ float s_ctx[NB_C + NB_K + 3 * NB_K];  // 320
  __shared__ int s_dec[4];
  __shared__ int s_vmode;

  int bn = blockIdx.x;
  int b = bn >> 3;
  int c = threadIdx.x;
  if (c == 0) s_vmode = validMode(valid);

  float denom = ws[WS_DEN + bn];
  float cand;
  if (denom <= 1e-5f) cand = ws[WS_VSUM + bn * NB_C + c] * (1.0f / NB_P);
  else                cand = ws[WS_WSUM + bn * NB_C + c] / fmaxf(denom, 1e-6f);
  float2 r0 = blk_sum2(cand * cand, 0.f, sbuf);
  cand *= 1.0f / fmaxf(sqrtf(r0.x), 1e-12f);
  s_cand[c] = cand;
  __syncthreads();
  int vmode = s_vmode;

  // cosine sims, wave-parallel: wave w owns k = 4w..4w+3
  const float* pr = proto + (size_t)bn * NB_K * NB_C;
  {
    int wid = c >> 6, lane = c & 63;
#pragma unroll
    for (int q = 0; q < 4; ++q) {
      int k = wid * 4 + q;
      float pp = 0.f, pc = 0.f;
#pragma unroll
      for (int t = 0; t < 4; ++t) {
        int cc = lane + t * 64;
        float p = pr[k * NB_C + cc];
        pp += p * p;
        pc += p * s_cand[cc];
      }
#pragma unroll
      for (int off = 32; off > 0; off >>= 1) {
        pp += __shfl_down(pp, off, 64);
        pc += __shfl_down(pc, off, 64);
      }
      if (lane == 0) {
        float invk = 1.0f / fmaxf(sqrtf(pp), 1e-12f);
        s_invn[k] = invk;
        s_sim[k] = getValid(valid, vmode, bn * NB_K + k) ? pc * invk : -1.0f;
      }
    }
  }

  float am = fmaxf(age[c], age[c + 256]);
  float um = fmaxf(usage[c], usage[c + 256]);
  float2 mx = blk_max2(am, um, sbuf);  // internal barrier orders s_sim/s_invn
  float age_max = fmaxf(mx.x, 1.0f);
  float use_max = fmaxf(mx.y, 1.0f);

  s_ctx[c] = ws[WS_GT + b * NB_C + c];
  if (c < NB_K) {
    int k = c;
    s_ctx[NB_C + k] = s_sim[k];
    s_ctx[NB_C + NB_K + 3 * k + 0] = age[bn * NB_K + k] / age_max;
    s_ctx[NB_C + NB_K + 3 * k + 1] = usage[bn * NB_K + k] / use_max;
    s_ctx[NB_C + NB_K + 3 * k + 2] = conf[bn * NB_K + k];
  }
  __syncthreads();

  float acc = b1[c];
  for (int i = 0; i < NB_C + 4 * NB_K; ++i) acc += s_ctx[i] * W1[i * 256 + c];
  float h = 0.5f * acc *
            (1.0f + tanhf(0.7978845608028654f * (acc + 0.044715f * acc * acc * acc)));
  for (int j = 0; j < 4; ++j) {
    float2 lj = blk_sum2(h * W2[c * 4 + j], 0.f, sbuf);
    if (c == 0) out_logits[bn * 4 + j] = lj.x + b2[j];
  }

  if (c == 0) {
    bool anyv = false, hasfree = false;
    for (int k = 0; k < NB_K; ++k) {
      if (getValid(valid, vmode, bn * NB_K + k)) anyv = true; else hasfree = true;
    }
    int tgt = 0; float best = s_sim[0];
    for (int k = 1; k < NB_K; ++k) if (s_sim[k] > best) { best = s_sim[k]; tgt = k; }
    if (!anyv) tgt = 0;
    float max_sim = anyv ? s_sim[tgt] : 0.0f;
    int action = 1;                       // REFINE
    if (max_sim > 0.85f) action = 0;      // KEEP
    bool low = max_sim < 0.5f;
    if (low && hasfree) action = 3;       // SPAWN
    if (low && !hasfree) action = 2;      // REPLACE
    int worst = 0; float wb = -1e30f;
    for (int k = 0; k < NB_K; ++k) {
      float sc = age[bn * NB_K + k] - usage[bn * NB_K + k] - conf[bn * NB_K + k] +
                 (getValid(valid, vmode, bn * NB_K + k) ? 0.f : 1000.f);
      if (sc > wb) { wb = sc; worst = k; }
    }
    int freeslot = 0;
    for (int k = 0; k < NB_K; ++k) {
      if (!getValid(valid, vmode, bn * NB_K + k)) { freeslot = k; break; }
    }
    int chosen = tgt;
    if (action == 3) chosen = hasfree ? freeslot : worst;
    if (action == 2) chosen = worst;
    s_dec[0] = chosen;
    s_dec[1] = (action == 1);
    s_dec[2] = (action == 2 || action == 3);
    s_dec[3] = (action != 0);
  }
  __syncthreads();

  int chosen = s_dec[0];
  float oldp = pr[chosen * NB_C + c];
  float t = 0.9f * oldp + 0.1f * s_cand[c];
  float2 tn = blk_sum2(t * t, 0.f, sbuf);
  float invt = 1.0f / fmaxf(sqrtf(tn.x), 1e-12f);
  float pn_chosen = s_dec[1] ? t * invt : (s_dec[2] ? s_cand[c] : oldp);
  float nb_chosen = s_dec[1] ? t * invt
                   : (s_dec[2] ? s_cand[c] : oldp * s_invn[chosen]);
  float nbrow[NB_K], pnrow[NB_K];
#pragma unroll
  for (int k = 0; k < NB_K; ++k) {
    float praw = pr[k * NB_C + c];
    nbrow[k] = (k == chosen) ? nb_chosen : praw * s_invn[k];
    pnrow[k] = (k == chosen) ? pn_chosen : praw;
  }
  float* nbp = ws + WS_NB + (size_t)bn * NB_K * NB_C + c * NB_K;
  float* pnp = ws + WS_PN + (size_t)bn * NB_K * NB_C + c * NB_K;
#pragma unroll
  for (int q = 0; q < 4; ++q) {
    *(float4*)(nbp + 4 * q) =
        make_float4(nbrow[4 * q], nbrow[4 * q + 1], nbrow[4 * q + 2], nbrow[4 * q + 3]);
    *(float4*)(pnp + 4 * q) =
        make_float4(pnrow[4 * q], pnrow[4 * q + 1], pnrow[4 * q + 2], pnrow[4 * q + 3]);
  }
  if (c < NB_K) {
    bool v = getValid(valid, vmode, bn * NB_K + c) || (c == chosen && s_dec[3]);
    ws[WS_VAL + bn * NB_K + c] = v ? 1.0f : 0.0f;
  }
}

// ---------------- kernel 3: fused readout, px-contiguous, k-split, 128-px tiles ---
// Block = 4 waves covering the SAME 128 contiguous px (lane owns 2 px / float2).
// Pass 1: wave wv computes dots for k=4wv..4wv+3 over ALL 256 channels (512 B
// contiguous loads; nb reads wave-uniform broadcasts). LDS partial exchange.
// Pass 2: wave wv applies its 64-channel quarter (pn broadcast, NT stores).
// Grid = 32 bn x 32 pxtiles = 1024 blocks -> 4 blocks/CU (LDS 26 KB), 16 waves/CU.
__global__ __launch_bounds__(256, 4) void k3_fused(
    const float* __restrict__ value, const float* __restrict__ frame,
    const float* __restrict__ ws, const float* __restrict__ pgp,
    const float* __restrict__ fgp, float* __restrict__ out) {
  __shared__ float s_nb[NB_C * NB_K];     // 16 KB: nb (pass 1), pn (pass 2)
  __shared__ float2 s_part[4][64][5];     // 10 KB padded partials
  int blk = blockIdx.x;
  int bn = blk >> 5, pxc = blk & 31;
  int b = bn >> 3;
  int tid = threadIdx.x;
  int lane = tid & 63, wv = tid >> 6;
  int px = pxc * 128 + lane * 2;

  const float4* nb4 = (const float4*)(ws + WS_NB + (size_t)bn * NB_K * NB_C);
  const float4* pn4 = (const float4*)(ws + WS_PN + (size_t)bn * NB_K * NB_C);
  float4* snb4 = (float4*)s_nb;
#pragma unroll
  for (int j = 0; j < 4; ++j) snb4[j * 256 + tid] = nb4[j * 256 + tid];
  int vmask = 0;
  for (int k = 0; k < NB_K; ++k)
    if (ws[WS_VAL + bn * NB_K + k] != 0.0f) vmask |= (1 << k);
  float pg = pgp[0], fg = fgp[0];
  __syncthreads();

  // pass 1: all 256 channels, this wave's 4 k's; 512 B contiguous loads
  const float* vp = value + (size_t)bn * NB_C * NB_P + px;
  const float* nbk = s_nb + wv * 4;  // [c][k] element c*16 + wv*4
  float2 dq0 = make_float2(0.f, 0.f);
  float2 dq1 = dq0, dq2 = dq0, dq3 = dq0, ss = dq0;
#pragma unroll 8
  for (int c = 0; c < NB_C; ++c) {
    float2 v = *(const float2*)(vp + (size_t)c * NB_P);
    float4 nk = *(const float4*)(nbk + c * NB_K);  // wave-uniform broadcast
    ss.x += v.x * v.x; ss.y += v.y * v.y;
    dq0.x += v.x * nk.x; dq0.y += v.y * nk.x;
    dq1.x += v.x * nk.y; dq1.y += v.y * nk.y;
    dq2.x += v.x * nk.z; dq2.y += v.y * nk.z;
    dq3.x += v.x * nk.w; dq3.y += v.y * nk.w;
  }

  // exchange partial dots (ss complete per wave: every wave read all channels)
  s_part[wv][lane][0] = dq0;
  s_part[wv][lane][1] = dq1;
  s_part[wv][lane][2] = dq2;
  s_part[wv][lane][3] = dq3;
  __syncthreads();  // pass-1 s_nb reads done; partials visible

  float2 d[NB_K];
#pragma unroll
  for (int k = 0; k < NB_K; ++k) d[k] = s_part[k >> 2][lane][k & 3];

  // restage pn into s_nb (overlaps softmax; no reader until next barrier)
#pragma unroll
  for (int j = 0; j < 4; ++j) snb4[j * 256 + tid] = pn4[j * 256 + tid];

  // softmax over K per pixel (in registers; lane owns its 2 px)
  float2 invv;
  invv.x = 1.0f / fmaxf(sqrtf(ss.x), 1e-12f);
  invv.y = 1.0f / fmaxf(sqrtf(ss.y), 1e-12f);
  float2 m = make_float2(-1e30f, -1e30f);
#pragma unroll
  for (int k = 0; k < NB_K; ++k) {
    d[k].x *= invv.x; d[k].y *= invv.y;
    if ((vmask >> k) & 1) {
      m.x = fmaxf(m.x, d[k].x); m.y = fmaxf(m.y, d[k].y);
    }
  }
  float2 es = make_float2(0.f, 0.f);
#pragma unroll
  for (int k = 0; k < NB_K; ++k) {
    if ((vmask >> k) & 1) {
      d[k].x = __expf(d[k].x - m.x); d[k].y = __expf(d[k].y - m.y);
      es.x += d[k].x; es.y += d[k].y;
    } else {
      d[k] = make_float2(0.f, 0.f);
    }
  }
  float2 isum;
  isum.x = vmask ? (1.0f / es.x) : 0.0f;
  isum.y = vmask ? (1.0f / es.y) : 0.0f;
#pragma unroll
  for (int k = 0; k < NB_K; ++k) { d[k].x *= isum.x; d[k].y *= isum.y; }
  __syncthreads();  // pn visible

  // pass 2: this wave's 64-channel quarter; pn broadcast; NT contiguous stores
  int c0 = wv * 64;
  const float* vp2 = value + ((size_t)bn * NB_C + c0) * NB_P + px;
  const float* fp = frame + ((size_t)b * NB_C + c0) * NB_P + px;
  float* op = out + ((size_t)bn * NB_C + c0) * NB_P + px;
  const float* spn = s_nb + (size_t)c0 * NB_K;
#pragma unroll 4
  for (int cc = 0; cc < 64; ++cc) {
    float2 v = *(const float2*)(vp2 + (size_t)cc * NB_P);
    float2 f = *(const float2*)(fp + (size_t)cc * NB_P);
    const float4* prow = (const float4*)(spn + cc * NB_K);
    float4 p0 = prow[0], p1 = prow[1], p2 = prow[2], p3 = prow[3];
    float2 pm = make_float2(0.f, 0.f);
#define APM(K, S)                                                        \
    pm.x += d[K].x * S; pm.y += d[K].y * S;
    APM(0, p0.x)  APM(1, p0.y)  APM(2, p0.z)  APM(3, p0.w)
    APM(4, p1.x)  APM(5, p1.y)  APM(6, p1.z)  APM(7, p1.w)
    APM(8, p2.x)  APM(9, p2.y)  APM(10, p2.z) APM(11, p2.w)
    APM(12, p3.x) APM(13, p3.y) APM(14, p3.z) APM(15, p3.w)
#undef APM
    nfloat2 o;
    o.x = v.x + pg * pm.x + fg * f.x;
    o.y = v.y + pg * pm.y + fg * f.y;
    __builtin_nontemporal_store(o, (nfloat2*)(op + (size_t)cc * NB_P));
  }
}

extern "C" void kernel_launch(void* const* d_in, const int* in_sizes, int n_in,
                              void* d_out, int out_size, void* d_ws, size_t ws_size,
                              hipStream_t stream) {
  const float* value = (const float*)d_in[0];
  const float* frame = (const float*)d_in[1];
  const float* mask  = (const float*)d_in[2];
  const float* proto = (const float*)d_in[3];
  const float* age   = (const float*)d_in[4];
  const float* usage = (const float*)d_in[5];
  const float* conf  = (const float*)d_in[6];
  const void*  valid = (const void*)d_in[7];
  const float* W1 = (const float*)d_in[8];
  const float* b1 = (const float*)d_in[9];
  const float* W2 = (const float*)d_in[10];
  const float* b2 = (const float*)d_in[11];
  const float* pg = (const float*)d_in[12];
  const float* fg = (const float*)d_in[13];
  float* out = (float*)d_out;
  float* ws = (float*)d_ws;

  int g1 = NB_BN * NB_C + NB_B * NB_C + NB_BN;  // 9248
  hipLaunchKernelGGL(k1_reduce, dim3(g1), dim3(256), 0, stream,
                     value, frame, mask, ws);
  hipLaunchKernelGGL(k2_policy, dim3(NB_BN), dim3(256), 0, stream,
                     proto, age, usage, conf, valid, W1, b1, W2, b2, ws,
                     out + (size_t)NB_BN * NB_C * NB_P);
  hipLaunchKernelGGL(k3_fused, dim3(NB_BN * 32), dim3(256), 0, stream,
                     value, frame, ws, pg, fg, out);
}

// Round 12
// 125.541 us; speedup vs baseline: 1.0835x; 1.0835x over previous
//
#include <hip/hip_runtime.h>
#include <math.h>

#define NB_B 4
#define NB_N 8
#define NB_C 256
#define NB_K 16
#define NB_P 4096
#define NB_BN (NB_B * NB_N)

typedef float nfloat4 __attribute__((ext_vector_type(4)));  // NT-store-able

// workspace float offsets
#define WS_WSUM 0
#define WS_VSUM (NB_BN * NB_C)                    // 8192
#define WS_GT   (2 * NB_BN * NB_C)                // 16384
#define WS_DEN  (WS_GT + NB_B * NB_C)             // 17408
#define WS_NB   17440                             // normalized bank, [bn][c][k]
#define WS_PN   (WS_NB + NB_BN * NB_K * NB_C)     // 148512: proto_new, [bn][c][k]
#define WS_VAL  (WS_PN + NB_BN * NB_K * NB_C)     // 279584

// async global->LDS, 16B per lane; LDS dest wave-uniform base + lane*16,
// global src per-lane. Compiler manages waitcnt (drained at __syncthreads).
__device__ __forceinline__ void stage16(const float* g, float* l) {
  __builtin_amdgcn_global_load_lds(
      (const __attribute__((address_space(1))) unsigned int*)g,
      (__attribute__((address_space(3))) unsigned int*)l, 16, 0, 0);
}

// ---------------- block reduction helpers (blockDim == 256, 4 waves) ----------------
__device__ __forceinline__ float2 blk_sum2(float a, float b, float2* sbuf) {
#pragma unroll
  for (int off = 32; off > 0; off >>= 1) {
    a += __shfl_down(a, off, 64);
    b += __shfl_down(b, off, 64);
  }
  int lane = threadIdx.x & 63, wid = threadIdx.x >> 6;
  __syncthreads();
  if (lane == 0) sbuf[wid] = make_float2(a, b);
  __syncthreads();
  float2 r;
  r.x = sbuf[0].x + sbuf[1].x + sbuf[2].x + sbuf[3].x;
  r.y = sbuf[0].y + sbuf[1].y + sbuf[2].y + sbuf[3].y;
  return r;
}

__device__ __forceinline__ float2 blk_max2(float a, float b, float2* sbuf) {
#pragma unroll
  for (int off = 32; off > 0; off >>= 1) {
    a = fmaxf(a, __shfl_down(a, off, 64));
    b = fmaxf(b, __shfl_down(b, off, 64));
  }
  int lane = threadIdx.x & 63, wid = threadIdx.x >> 6;
  __syncthreads();
  if (lane == 0) sbuf[wid] = make_float2(a, b);
  __syncthreads();
  float2 r;
  r.x = fmaxf(fmaxf(sbuf[0].x, sbuf[1].x), fmaxf(sbuf[2].x, sbuf[3].x));
  r.y = fmaxf(fmaxf(sbuf[0].y, sbuf[1].y), fmaxf(sbuf[2].y, sbuf[3].y));
  return r;
}

// ---------------- robust decoding of the bool `valid` input ----------------
__device__ __forceinline__ int validMode(const void* vptr) {
  const unsigned int* w = (const unsigned int*)vptr;
  int mode = 0;  // 0 = int32
  for (int i = 0; i < 128; ++i) {
    unsigned int x = w[i];
    if (x == 0x3f800000u) return 2;      // float32 1.0 present -> f32
    if (x > 1u) mode = 1;                // packed bytes -> uint8
  }
  return mode;
}
__device__ __forceinline__ bool getValid(const void* vptr, int mode, int idx) {
  if (mode == 1) return ((const unsigned char*)vptr)[idx] != 0;
  if (mode == 2) return ((const float*)vptr)[idx] != 0.0f;
  return ((const int*)vptr)[idx] != 0;
}

// ---------------- kernel 1: big reductions over P (known-good) ----------------
__global__ __launch_bounds__(256) void k1_reduce(
    const float* __restrict__ value, const float* __restrict__ frame,
    const float* __restrict__ mask, float* __restrict__ ws) {
  __shared__ float2 sbuf[4];
  int gid = blockIdx.x, tid = threadIdx.x;
  if (gid < NB_BN * NB_C) {
    int bn = gid >> 8;
    const float4* v4 = (const float4*)(value + (size_t)gid * NB_P);
    const float4* m4 = (const float4*)(mask + (size_t)bn * NB_P);
    float wsum = 0.f, vsum = 0.f;
#pragma unroll
    for (int i = 0; i < NB_P / 4 / 256; ++i) {
      float4 a = v4[i * 256 + tid];
      float4 m = m4[i * 256 + tid];
      wsum += a.x * m.x + a.y * m.y + a.z * m.z + a.w * m.w;
      vsum += a.x + a.y + a.z + a.w;
    }
    float2 r = blk_sum2(wsum, vsum, sbuf);
    if (tid == 0) { ws[WS_WSUM + gid] = r.x; ws[WS_VSUM + gid] = r.y; }
  } else if (gid < NB_BN * NB_C + NB_B * NB_C) {
    int idx = gid - NB_BN * NB_C;
    const float4* f4 = (const float4*)(frame + (size_t)idx * NB_P);
    float s = 0.f;
#pragma unroll
    for (int i = 0; i < 4; ++i) {
      float4 a = f4[i * 256 + tid];
      s += a.x + a.y + a.z + a.w;
    }
    float2 r = blk_sum2(s, 0.f, sbuf);
    if (tid == 0) ws[WS_GT + idx] = r.x * (1.0f / NB_P);
  } else {
    int bn = gid - NB_BN * NB_C - NB_B * NB_C;
    const float4* m4 = (const float4*)(mask + (size_t)bn * NB_P);
    float s = 0.f;
#pragma unroll
    for (int i = 0; i < 4; ++i) {
      float4 a = m4[i * 256 + tid];
      s += a.x + a.y + a.z + a.w;
    }
    float2 r = blk_sum2(s, 0.f, sbuf);
    if (tid == 0) ws[WS_DEN + bn] = r.x;
  }
}

// ---------------- kernel 2: per-(b,n) policy + bank update ----------------
__global__ __launch_bounds__(256) void k2_policy(
    const float* __restrict__ proto, const float* __restrict__ age,
    const float* __restrict__ usage, const float* __restrict__ conf,
    const void* __restrict__ valid, const float* __restrict__ W1,
    const float* __restrict__ b1, const float* __restrict__ W2,
    const float* __restrict__ b2, float* __restrict__ ws,
    float* __restrict__ out_logits) {
  __shared__ float2 sbuf[4];
  __shared__ float s_cand[NB_C];
  __shared__ float s_sim[NB_K];
  __shared__ float s_invn[NB_K];
  __shared__ float s_ctx[NB_C + NB_K + 3 * NB_K];  // 320
  __shared__ int s_dec[4];
  __shared__ int s_vmode;

  int bn = blockIdx.x;
  int b = bn >> 3;
  int c = threadIdx.x;
  if (c == 0) s_vmode = validMode(valid);

  float denom = ws[WS_DEN + bn];
  float cand;
  if (denom <= 1e-5f) cand = ws[WS_VSUM + bn * NB_C + c] * (1.0f / NB_P);
  else                cand = ws[WS_WSUM + bn * NB_C + c] / fmaxf(denom, 1e-6f);
  float2 r0 = blk_sum2(cand * cand, 0.f, sbuf);
  cand *= 1.0f / fmaxf(sqrtf(r0.x), 1e-12f);
  s_cand[c] = cand;
  __syncthreads();
  int vmode = s_vmode;

  // cosine sims, wave-parallel: wave w owns k = 4w..4w+3
  const float* pr = proto + (size_t)bn * NB_K * NB_C;
  {
    int wid = c >> 6, lane = c & 63;
#pragma unroll
    for (int q = 0; q < 4; ++q) {
      int k = wid * 4 + q;
      float pp = 0.f, pc = 0.f;
#pragma unroll
      for (int t = 0; t < 4; ++t) {
        int cc = lane + t * 64;
        float p = pr[k * NB_C + cc];
        pp += p * p;
        pc += p * s_cand[cc];
      }
#pragma unroll
      for (int off = 32; off > 0; off >>= 1) {
        pp += __shfl_down(pp, off, 64);
        pc += __shfl_down(pc, off, 64);
      }
      if (lane == 0) {
        float invk = 1.0f / fmaxf(sqrtf(pp), 1e-12f);
        s_invn[k] = invk;
        s_sim[k] = getValid(valid, vmode, bn * NB_K + k) ? pc * invk : -1.0f;
      }
    }
  }

  float am = fmaxf(age[c], age[c + 256]);
  float um = fmaxf(usage[c], usage[c + 256]);
  float2 mx = blk_max2(am, um, sbuf);  // internal barrier orders s_sim/s_invn
  float age_max = fmaxf(mx.x, 1.0f);
  float use_max = fmaxf(mx.y, 1.0f);

  s_ctx[c] = ws[WS_GT + b * NB_C + c];
  if (c < NB_K) {
    int k = c;
    s_ctx[NB_C + k] = s_sim[k];
    s_ctx[NB_C + NB_K + 3 * k + 0] = age[bn * NB_K + k] / age_max;
    s_ctx[NB_C + NB_K + 3 * k + 1] = usage[bn * NB_K + k] / use_max;
    s_ctx[NB_C + NB_K + 3 * k + 2] = conf[bn * NB_K + k];
  }
  __syncthreads();

  float acc = b1[c];
  for (int i = 0; i < NB_C + 4 * NB_K; ++i) acc += s_ctx[i] * W1[i * 256 + c];
  float h = 0.5f * acc *
            (1.0f + tanhf(0.7978845608028654f * (acc + 0.044715f * acc * acc * acc)));
  for (int j = 0; j < 4; ++j) {
    float2 lj = blk_sum2(h * W2[c * 4 + j], 0.f, sbuf);
    if (c == 0) out_logits[bn * 4 + j] = lj.x + b2[j];
  }

  if (c == 0) {
    bool anyv = false, hasfree = false;
    for (int k = 0; k < NB_K; ++k) {
      if (getValid(valid, vmode, bn * NB_K + k)) anyv = true; else hasfree = true;
    }
    int tgt = 0; float best = s_sim[0];
    for (int k = 1; k < NB_K; ++k) if (s_sim[k] > best) { best = s_sim[k]; tgt = k; }
    if (!anyv) tgt = 0;
    float max_sim = anyv ? s_sim[tgt] : 0.0f;
    int action = 1;                       // REFINE
    if (max_sim > 0.85f) action = 0;      // KEEP
    bool low = max_sim < 0.5f;
    if (low && hasfree) action = 3;       // SPAWN
    if (low && !hasfree) action = 2;      // REPLACE
    int worst = 0; float wb = -1e30f;
    for (int k = 0; k < NB_K; ++k) {
      float sc = age[bn * NB_K + k] - usage[bn * NB_K + k] - conf[bn * NB_K + k] +
                 (getValid(valid, vmode, bn * NB_K + k) ? 0.f : 1000.f);
      if (sc > wb) { wb = sc; worst = k; }
    }
    int freeslot = 0;
    for (int k = 0; k < NB_K; ++k) {
      if (!getValid(valid, vmode, bn * NB_K + k)) { freeslot = k; break; }
    }
    int chosen = tgt;
    if (action == 3) chosen = hasfree ? freeslot : worst;
    if (action == 2) chosen = worst;
    s_dec[0] = chosen;
    s_dec[1] = (action == 1);
    s_dec[2] = (action == 2 || action == 3);
    s_dec[3] = (action != 0);
  }
  __syncthreads();

  int chosen = s_dec[0];
  float oldp = pr[chosen * NB_C + c];
  float t = 0.9f * oldp + 0.1f * s_cand[c];
  float2 tn = blk_sum2(t * t, 0.f, sbuf);
  float invt = 1.0f / fmaxf(sqrtf(tn.x), 1e-12f);
  float pn_chosen = s_dec[1] ? t * invt : (s_dec[2] ? s_cand[c] : oldp);
  float nb_chosen = s_dec[1] ? t * invt
                   : (s_dec[2] ? s_cand[c] : oldp * s_invn[chosen]);
  float nbrow[NB_K], pnrow[NB_K];
#pragma unroll
  for (int k = 0; k < NB_K; ++k) {
    float praw = pr[k * NB_C + c];
    nbrow[k] = (k == chosen) ? nb_chosen : praw * s_invn[k];
    pnrow[k] = (k == chosen) ? pn_chosen : praw;
  }
  float* nbp = ws + WS_NB + (size_t)bn * NB_K * NB_C + c * NB_K;
  float* pnp = ws + WS_PN + (size_t)bn * NB_K * NB_C + c * NB_K;
#pragma unroll
  for (int q = 0; q < 4; ++q) {
    *(float4*)(nbp + 4 * q) =
        make_float4(nbrow[4 * q], nbrow[4 * q + 1], nbrow[4 * q + 2], nbrow[4 * q + 3]);
    *(float4*)(pnp + 4 * q) =
        make_float4(pnrow[4 * q], pnrow[4 * q + 1], pnrow[4 * q + 2], pnrow[4 * q + 3]);
  }
  if (c < NB_K) {
    bool v = getValid(valid, vmode, bn * NB_K + c) || (c == chosen && s_dec[3]);
    ws[WS_VAL + bn * NB_K + c] = v ? 1.0f : 0.0f;
  }
}

// ---------------- kernel 3: fused readout, DMA-staged pass 1 ----------------
// Block = 4 waves, 256 contiguous px (lane owns 4 px / float4).
// Pass 1: value staged into LDS via global_load_lds in 16-row (16 KB) chunks,
// double-buffered, compiler-managed waitcnt at __syncthreads (m97 pattern).
// All 4 waves consume the shared tile; wave wv accumulates its 4 of 16 k-dots
// (20 VGPR acc). Partials exchanged via LDS; softmax in registers.
// Pass 2: round-10 form (direct float4 loads, wave c-quarter, NT stores).
__global__ __launch_bounds__(256) void k3_fused(
    const float* __restrict__ value, const float* __restrict__ frame,
    const float* __restrict__ ws, const float* __restrict__ pgp,
    const float* __restrict__ fgp, float* __restrict__ out) {
  __shared__ float s_nb[NB_C * NB_K];      // 16 KB: nb (pass 1), pn (pass 2)
  __shared__ float s_vbuf[2][16][256];     // 32 KB: double-buffered value tile
  __shared__ float s_ex[17][256];          // 17 KB: partial-dot exchange
  int blk = blockIdx.x;
  int bn = blk >> 4, pxc = blk & 15;
  int b = bn >> 3;
  int tid = threadIdx.x;
  int lane = tid & 63, wv = tid >> 6;
  int px0 = pxc * 256;
  int px = px0 + lane * 4;

  const float4* nb4 = (const float4*)(ws + WS_NB + (size_t)bn * NB_K * NB_C);
  const float4* pn4 = (const float4*)(ws + WS_PN + (size_t)bn * NB_K * NB_C);
  float4* snb4 = (float4*)s_nb;
#pragma unroll
  for (int j = 0; j < 4; ++j) snb4[j * 256 + tid] = nb4[j * 256 + tid];
  int vmask = 0;
  for (int k = 0; k < NB_K; ++k)
    if (ws[WS_VAL + bn * NB_K + k] != 0.0f) vmask |= (1 << k);
  float pg = pgp[0], fg = fgp[0];

  const float* vrow = value + (size_t)bn * NB_C * NB_P + px0;

  // prologue: stage chunk 0 (rows 0..15): wave wv stages rows 4wv..4wv+3
#pragma unroll
  for (int j = 0; j < 4; ++j)
    stage16(vrow + (size_t)(4 * wv + j) * NB_P + lane * 4,
            &s_vbuf[0][4 * wv + j][0]);
  __syncthreads();  // nb visible; chunk-0 DMA drained

  // pass 1: 16 chunks x 16 rows; wave wv accumulates k = 4wv..4wv+3
  const float* nbk = s_nb + wv * 4;
  float4 dq0 = make_float4(0.f, 0.f, 0.f, 0.f);
  float4 dq1 = dq0, dq2 = dq0, dq3 = dq0, ss = dq0;
  int cur = 0;
  for (int ch = 0; ch < 16; ++ch) {
    if (ch < 15) {
#pragma unroll
      for (int j = 0; j < 4; ++j) {
        int r = (ch + 1) * 16 + 4 * wv + j;
        stage16(vrow + (size_t)r * NB_P + lane * 4,
                &s_vbuf[cur ^ 1][4 * wv + j][0]);
      }
    }
    const float* vb = &s_vbuf[cur][0][0];
#pragma unroll
    for (int r = 0; r < 16; ++r) {
      int c = ch * 16 + r;
      float4 v = *(const float4*)(vb + r * 256 + (lane << 2));
      float4 nk = *(const float4*)(nbk + c * NB_K);  // wave-uniform broadcast
      ss.x += v.x * v.x; ss.y += v.y * v.y; ss.z += v.z * v.z; ss.w += v.w * v.w;
      dq0.x += v.x * nk.x; dq0.y += v.y * nk.x; dq0.z += v.z * nk.x; dq0.w += v.w * nk.x;
      dq1.x += v.x * nk.y; dq1.y += v.y * nk.y; dq1.z += v.z * nk.y; dq1.w += v.w * nk.y;
      dq2.x += v.x * nk.z; dq2.y += v.y * nk.z; dq2.z += v.z * nk.z; dq2.w += v.w * nk.z;
      dq3.x += v.x * nk.w; dq3.y += v.y * nk.w; dq3.z += v.z * nk.w; dq3.w += v.w * nk.w;
    }
    __syncthreads();  // next-chunk DMA drained; all reads of cur done
    cur ^= 1;
  }

  // exchange partial dots: wave wv owns rows 4wv..4wv+3 of s_ex
  *(float4*)&s_ex[4 * wv + 0][lane << 2] = dq0;
  *(float4*)&s_ex[4 * wv + 1][lane << 2] = dq1;
  *(float4*)&s_ex[4 * wv + 2][lane << 2] = dq2;
  *(float4*)&s_ex[4 * wv + 3][lane << 2] = dq3;
  // restage pn into s_nb (pass-1 nk reads completed before last barrier)
  float4 pnr[4];
#pragma unroll
  for (int j = 0; j < 4; ++j) pnr[j] = pn4[j * 256 + tid];
#pragma unroll
  for (int j = 0; j < 4; ++j) snb4[j * 256 + tid] = pnr[j];
  __syncthreads();  // s_ex + pn visible

  float4 d[NB_K];
#pragma unroll
  for (int k = 0; k < NB_K; ++k) d[k] = *(const float4*)&s_ex[k][lane << 2];

  // softmax over K per pixel (in registers; lane owns its 4 px; ss complete)
  float4 invv;
  invv.x = 1.0f / fmaxf(sqrtf(ss.x), 1e-12f);
  invv.y = 1.0f / fmaxf(sqrtf(ss.y), 1e-12f);
  invv.z = 1.0f / fmaxf(sqrtf(ss.z), 1e-12f);
  invv.w = 1.0f / fmaxf(sqrtf(ss.w), 1e-12f);
  float4 m = make_float4(-1e30f, -1e30f, -1e30f, -1e30f);
#pragma unroll
  for (int k = 0; k < NB_K; ++k) {
    d[k].x *= invv.x; d[k].y *= invv.y; d[k].z *= invv.z; d[k].w *= invv.w;
    if ((vmask >> k) & 1) {
      m.x = fmaxf(m.x, d[k].x); m.y = fmaxf(m.y, d[k].y);
      m.z = fmaxf(m.z, d[k].z); m.w = fmaxf(m.w, d[k].w);
    }
  }
  float4 es = make_float4(0.f, 0.f, 0.f, 0.f);
#pragma unroll
  for (int k = 0; k < NB_K; ++k) {
    if ((vmask >> k) & 1) {
      d[k].x = __expf(d[k].x - m.x); d[k].y = __expf(d[k].y - m.y);
      d[k].z = __expf(d[k].z - m.z); d[k].w = __expf(d[k].w - m.w);
      es.x += d[k].x; es.y += d[k].y; es.z += d[k].z; es.w += d[k].w;
    } else {
      d[k] = make_float4(0.f, 0.f, 0.f, 0.f);
    }
  }
  float4 isum;
  isum.x = vmask ? (1.0f / es.x) : 0.0f;
  isum.y = vmask ? (1.0f / es.y) : 0.0f;
  isum.z = vmask ? (1.0f / es.z) : 0.0f;
  isum.w = vmask ? (1.0f / es.w) : 0.0f;
#pragma unroll
  for (int k = 0; k < NB_K; ++k) {
    d[k].x *= isum.x; d[k].y *= isum.y; d[k].z *= isum.z; d[k].w *= isum.w;
  }

  // pass 2: this wave's 64-channel quarter; pn broadcast; NT contiguous stores
  int c0 = wv * 64;
  const float* vp2 = value + ((size_t)bn * NB_C + c0) * NB_P + px;
  const float* fp = frame + ((size_t)b * NB_C + c0) * NB_P + px;
  float* op = out + ((size_t)bn * NB_C + c0) * NB_P + px;
  const float* spn = s_nb + (size_t)c0 * NB_K;
#pragma unroll 4
  for (int cc = 0; cc < 64; ++cc) {
    float4 v = *(const float4*)(vp2 + (size_t)cc * NB_P);
    float4 f = *(const float4*)(fp + (size_t)cc * NB_P);
    const float4* prow = (const float4*)(spn + cc * NB_K);
    float4 p0 = prow[0], p1 = prow[1], p2 = prow[2], p3 = prow[3];
    float4 pm = make_float4(0.f, 0.f, 0.f, 0.f);
#define APM(K, S)                                                        \
    pm.x += d[K].x * S; pm.y += d[K].y * S; pm.z += d[K].z * S; pm.w += d[K].w * S;
    APM(0, p0.x)  APM(1, p0.y)  APM(2, p0.z)  APM(3, p0.w)
    APM(4, p1.x)  APM(5, p1.y)  APM(6, p1.z)  APM(7, p1.w)
    APM(8, p2.x)  APM(9, p2.y)  APM(10, p2.z) APM(11, p2.w)
    APM(12, p3.x) APM(13, p3.y) APM(14, p3.z) APM(15, p3.w)
#undef APM
    nfloat4 o;
    o.x = v.x + pg * pm.x + fg * f.x;
    o.y = v.y + pg * pm.y + fg * f.y;
    o.z = v.z + pg * pm.z + fg * f.z;
    o.w = v.w + pg * pm.w + fg * f.w;
    __builtin_nontemporal_store(o, (nfloat4*)(op + (size_t)cc * NB_P));
  }
}

extern "C" void kernel_launch(void* const* d_in, const int* in_sizes, int n_in,
                              void* d_out, int out_size, void* d_ws, size_t ws_size,
                              hipStream_t stream) {
  const float* value = (const float*)d_in[0];
  const float* frame = (const float*)d_in[1];
  const float* mask  = (const float*)d_in[2];
  const float* proto = (const float*)d_in[3];
  const float* age   = (const float*)d_in[4];
  const float* usage = (const float*)d_in[5];
  const float* conf  = (const float*)d_in[6];
  const void*  valid = (const void*)d_in[7];
  const float* W1 = (const float*)d_in[8];
  const float* b1 = (const float*)d_in[9];
  const float* W2 = (const float*)d_in[10];
  const float* b2 = (const float*)d_in[11];
  const float* pg = (const float*)d_in[12];
  const float* fg = (const float*)d_in[13];
  float* out = (float*)d_out;
  float* ws = (float*)d_ws;

  int g1 = NB_BN * NB_C + NB_B * NB_C + NB_BN;  // 9248
  hipLaunchKernelGGL(k1_reduce, dim3(g1), dim3(256), 0, stream,
                     value, frame, mask, ws);
  hipLaunchKernelGGL(k2_policy, dim3(NB_BN), dim3(256), 0, stream,
                     proto, age, usage, conf, valid, W1, b1, W2, b2, ws,
                     out + (size_t)NB_BN * NB_C * NB_P);
  hipLaunchKernelGGL(k3_fused, dim3(NB_BN * 16), dim3(256), 0, stream,
                     value, frame, ws, pg, fg, out);
}